// Round 1
// baseline (5050.859 us; speedup 1.0000x reference)
//
#include <hip/hip_runtime.h>
#include <math.h>

// ---------- float <-> order-preserving uint key (for atomic max/min) ----------
__device__ __forceinline__ unsigned fkey(float x) {
  int b = __float_as_int(x);
  return (unsigned)(b ^ ((b >> 31) | 0x80000000));
}
__device__ __forceinline__ float funkey(unsigned k) {
  int b = (k & 0x80000000u) ? (int)(k ^ 0x80000000u) : (int)(~k);
  return __int_as_float(b);
}

// ---------- K1: per-node pd/ps precompute ----------
// pd[n][t][g] = b_pre[t][g] + sum_f xt[n][t][f] * W_pre[t][f][g]        (dst part)
// ps[n][t][g] =               sum_f xt[n][t][f] * W_pre[t][32+f][g]     (src part)
__global__ __launch_bounds__(256) void pre_kernel(
    const float* __restrict__ x, const float* __restrict__ W_pre,
    const float* __restrict__ b_pre,
    float* __restrict__ pd, float* __restrict__ ps)
{
  __shared__ float xl[2][128];
  const int tid = threadIdx.x;
  const int nl  = tid >> 7;
  const int j   = tid & 127;
  const int n   = blockIdx.x * 2 + nl;
  xl[nl][j] = x[(size_t)n * 128 + j];
  __syncthreads();
  const int t = j >> 5, g = j & 31;
  const float* xp = &xl[nl][t * 32];
  const float* Wd = W_pre + (size_t)(t * 96) * 32 + g;      // rows 0..31
  const float* Ws = Wd + 32 * 32;                            // rows 32..63
  float apd = b_pre[t * 32 + g];
  float aps = 0.f;
#pragma unroll
  for (int f = 0; f < 32; ++f) {
    float xv = xp[f];
    apd += xv * Wd[f * 32];
    aps += xv * Ws[f * 32];
  }
  pd[(size_t)n * 128 + j] = apd;
  ps[(size_t)n * 128 + j] = aps;
}

// ---------- K2: edge kernel (1 wave per edge, uniform loop, atomic agg) ----------
__global__ __launch_bounds__(256) void edge_kernel(
    const float* __restrict__ edge_attr, const int* __restrict__ ei,
    const float* __restrict__ W_edge, const float* __restrict__ b_edge,
    const float* __restrict__ W_pre,
    const float* __restrict__ pd, const float* __restrict__ ps,
    float* __restrict__ ssum, float* __restrict__ ssq,
    unsigned* __restrict__ smax, unsigned* __restrict__ smin,
    int* __restrict__ cnt, int E)
{
  __shared__ float sEA[4][128];
  __shared__ float sEV[4][32];
  const int tid  = threadIdx.x;
  const int lane = tid & 63;
  const int w    = tid >> 6;
  const int nwaves = gridDim.x * 4;
  const int wave_global = blockIdx.x * 4 + w;
  const int epw = (E + nwaves - 1) / nwaves;   // uniform trip count for all waves
  const int e0  = wave_global * epw;
  const int g    = lane & 31;
  const int half = lane >> 5;
  const float bedge = b_edge[g];
  // W_pre "We" block (rows 64..95) column g, towers (half) and (half+2)
  const float* Wp0 = W_pre + (size_t)(half * 96 + 64) * 32 + g;
  const float* Wp1 = Wp0 + 2 * 96 * 32;

  for (int it = 0; it < epw; ++it) {
    const int e = e0 + it;
    const bool ok = (e < E);
    int s = 0, d = 0;
    if (ok) {
      s = ei[e];
      d = ei[E + e];
      const float* ea = edge_attr + (size_t)e * 128;
      sEA[w][lane]      = ea[lane];
      sEA[w][lane + 64] = ea[lane + 64];
    }
    __syncthreads();
    if (ok) {
      // e[g] = b_edge[g] + edge_attr_row . W_edge[g,:]; lanes split 128-dot in halves
      float acc = 0.f;
      const float* wE  = W_edge + (size_t)g * 128 + half * 64;
      const float* eap = &sEA[w][half * 64];
#pragma unroll
      for (int c = 0; c < 64; ++c) acc += eap[c] * wE[c];
      acc += __shfl_xor(acc, 32);
      if (lane < 32) sEV[w][g] = acc + bedge;
    }
    __syncthreads();
    if (ok) {
      // etrans + gathered pd/ps -> m for features j0=lane, j1=lane+64
      float a0 = 0.f, a1 = 0.f;
      const float* ev = sEV[w];
#pragma unroll
      for (int f = 0; f < 32; ++f) {
        float evf = ev[f];
        a0 += evf * Wp0[f * 32];
        a1 += evf * Wp1[f * 32];
      }
      const size_t bd = (size_t)d * 128;
      const size_t bs = (size_t)s * 128;
      float m0 = a0 + pd[bd + lane]      + ps[bs + lane];
      float m1 = a1 + pd[bd + 64 + lane] + ps[bs + 64 + lane];
      const size_t o0 = bd + lane, o1 = o0 + 64;
      unsafeAtomicAdd(&ssum[o0], m0);
      unsafeAtomicAdd(&ssum[o1], m1);
      unsafeAtomicAdd(&ssq[o0], m0 * m0);
      unsafeAtomicAdd(&ssq[o1], m1 * m1);
      unsigned k0 = fkey(m0), k1 = fkey(m1);
      atomicMax(&smax[o0], k0);
      atomicMax(&smax[o1], k1);
      atomicMin(&smin[o0], k0);
      atomicMin(&smin[o1], k1);
      if (lane == 0) atomicAdd(&cnt[d], 1);
    }
    __syncthreads();
  }
}

// ---------- K3: node kernel (8 nodes/block; scalers, W_post, W_lin, residual) ----------
__global__ __launch_bounds__(256) void node_kernel(
    const float* __restrict__ x,
    const float* __restrict__ ssum, const float* __restrict__ ssq,
    const unsigned* __restrict__ smax, const unsigned* __restrict__ smin,
    const int* __restrict__ cnt,
    const float* __restrict__ W_post, const float* __restrict__ b_post,
    const float* __restrict__ W_lin, const float* __restrict__ b_lin,
    float* __restrict__ out, float avg_log)
{
  __shared__ float vec[8][4][416];
  __shared__ float h2[8][128];
  const int tid = threadIdx.x;
  const int j = tid & 127;
  const int t = j >> 5, g = j & 31;
  const int n0 = blockIdx.x * 8;

  // phase 1: build the 416-feature per-tower vector for 8 nodes (2 per pass)
  for (int itn = 0; itn < 4; ++itn) {
    const int nl = itn * 2 + (tid >> 7);
    const int n = n0 + nl;
    const size_t o = (size_t)n * 128 + j;
    const float c = (float)cnt[n];
    const float csafe = fmaxf(c, 1.f);
    const float mean = ssum[o] / csafe;
    const float msq  = ssq[o] / csafe;
    const float sd = sqrtf(fmaxf(msq - mean * mean, 0.f) + 1e-5f);
    float mx, mn;
    if (c > 0.f) { mx = funkey(smax[o]); mn = funkey(smin[o]); }
    else         { mx = 0.f; mn = 0.f; }
    const float logd = logf(c + 1.f);
    const float amp_s = logd / avg_log;
    const float att_s = (c == 0.f) ? 1.f : (avg_log / logd);
    float* v = vec[nl][t];
    v[g]        = x[o];
    v[32 + g]   = mean;          v[64 + g]   = mx;
    v[96 + g]   = mn;            v[128 + g]  = sd;
    v[160 + g]  = mean * amp_s;  v[192 + g]  = mx * amp_s;
    v[224 + g]  = mn * amp_s;    v[256 + g]  = sd * amp_s;
    v[288 + g]  = mean * att_s;  v[320 + g]  = mx * att_s;
    v[352 + g]  = mn * att_s;    v[384 + g]  = sd * att_s;
  }
  __syncthreads();

  // phase 2: h2[n][t*32+g] = b_post + vec . W_post[t][:,g] ; 4 nodes per thread
  {
    const int nlb = tid >> 7;  // 0 or 1
    const float b = b_post[t * 32 + g];
    float acc0 = b, acc1 = b, acc2 = b, acc3 = b;
    const float* Wp = W_post + (size_t)(t * 416) * 32 + g;
    const float* v0 = vec[nlb + 0][t];
    const float* v1 = vec[nlb + 2][t];
    const float* v2 = vec[nlb + 4][t];
    const float* v3 = vec[nlb + 6][t];
    for (int f = 0; f < 416; ++f) {
      const float wv = Wp[(size_t)f * 32];
      acc0 += v0[f] * wv; acc1 += v1[f] * wv;
      acc2 += v2[f] * wv; acc3 += v3[f] * wv;
    }
    h2[nlb + 0][j] = acc0; h2[nlb + 2][j] = acc1;
    h2[nlb + 4][j] = acc2; h2[nlb + 6][j] = acc3;
  }
  __syncthreads();

  // phase 3: out[n][j] = b_lin[j] + x[n][j] + h2[n] . W_lin[j,:]
  {
    const int nlb = tid >> 7;
    const float* Wl = W_lin + (size_t)j * 128;
    const float bl = b_lin[j];
    float a0 = bl, a1 = bl, a2 = bl, a3 = bl;
    const float* h0 = h2[nlb + 0];
    const float* h1 = h2[nlb + 2];
    const float* h2p = h2[nlb + 4];
    const float* h3 = h2[nlb + 6];
    for (int k = 0; k < 128; ++k) {
      const float wv = Wl[k];
      a0 += h0[k] * wv; a1 += h1[k] * wv;
      a2 += h2p[k] * wv; a3 += h3[k] * wv;
    }
    const size_t b0 = (size_t)(n0 + nlb + 0) * 128 + j;
    const size_t b1 = (size_t)(n0 + nlb + 2) * 128 + j;
    const size_t b2 = (size_t)(n0 + nlb + 4) * 128 + j;
    const size_t b3 = (size_t)(n0 + nlb + 6) * 128 + j;
    out[b0] = a0 + x[b0];
    out[b1] = a1 + x[b1];
    out[b2] = a2 + x[b2];
    out[b3] = a3 + x[b3];
  }
}

extern "C" void kernel_launch(void* const* d_in, const int* in_sizes, int n_in,
                              void* d_out, int out_size, void* d_ws, size_t ws_size,
                              hipStream_t stream) {
  const float* x         = (const float*)d_in[0];
  const float* edge_attr = (const float*)d_in[1];
  const int*   ei        = (const int*)  d_in[2];
  const float* W_edge    = (const float*)d_in[3];
  const float* b_edge    = (const float*)d_in[4];
  const float* W_pre     = (const float*)d_in[5];
  const float* b_pre     = (const float*)d_in[6];
  const float* W_post    = (const float*)d_in[7];
  const float* b_post    = (const float*)d_in[8];
  const float* W_lin     = (const float*)d_in[9];
  const float* b_lin     = (const float*)d_in[10];
  float* out = (float*)d_out;

  const int N = in_sizes[0] / 128;
  const int E = in_sizes[2] / 2;

  // workspace layout (floats): pd, ps, ssum, ssq, smax, cnt, smin
  float* pd   = (float*)d_ws;
  float* ps   = pd + (size_t)N * 128;
  float* ssum = ps + (size_t)N * 128;
  float* ssq  = ssum + (size_t)N * 128;
  unsigned* smax = (unsigned*)(ssq + (size_t)N * 128);
  int* cnt = (int*)(smax + (size_t)N * 128);
  unsigned* smin = (unsigned*)(cnt + N);

  // init aggregation buffers: ssum/ssq/smaxkey/cnt -> 0, sminkey -> 0xFFFFFFFF
  const size_t zero_bytes = ((size_t)N * 128 * 3 + N) * 4;
  hipMemsetAsync(ssum, 0, zero_bytes, stream);
  hipMemsetAsync(smin, 0xFF, (size_t)N * 128 * 4, stream);

  // AVG_LOG in double on host (graph-safe: pure CPU, same every call)
  const double counts[6] = {108477.0, 299931.0, 180702.0, 10767.0, 3.0, 2.0};
  double num = 0.0, den = 0.0;
  for (int i = 0; i < 6; ++i) { num += counts[i] * log((double)(i + 2)); den += counts[i]; }
  const float avg_log = (float)(num / den);

  pre_kernel<<<N / 2, 256, 0, stream>>>(x, W_pre, b_pre, pd, ps);
  edge_kernel<<<2048, 256, 0, stream>>>(edge_attr, ei, W_edge, b_edge, W_pre,
                                        pd, ps, ssum, ssq, smax, smin, cnt, E);
  node_kernel<<<N / 8, 256, 0, stream>>>(x, ssum, ssq, smax, smin, cnt,
                                         W_post, b_post, W_lin, b_lin, out, avg_log);
}

// Round 2
// 2034.136 us; speedup vs baseline: 2.4830x; 2.4830x over previous
//
#include <hip/hip_runtime.h>
#include <math.h>

// ============================================================
// K1: ps[n][j] = sum_f xt[n][t][f] * W_pre[t][32+f][g]   (src-part, gathered later)
// ============================================================
__global__ __launch_bounds__(256) void pre_kernel(
    const float* __restrict__ x, const float* __restrict__ W_pre,
    float* __restrict__ ps)
{
  __shared__ float xl[2][128];
  const int tid = threadIdx.x;
  const int nl  = tid >> 7;
  const int j   = tid & 127;
  const int n   = blockIdx.x * 2 + nl;
  xl[nl][j] = x[(size_t)n * 128 + j];
  __syncthreads();
  const int t = j >> 5, g = j & 31;
  const float* xp = &xl[nl][t * 32];
  const float* Ws = W_pre + (size_t)(t * 96 + 32) * 32 + g;   // rows 32..63
  float aps = 0.f;
#pragma unroll
  for (int f = 0; f < 32; ++f) aps += xp[f] * Ws[f * 32];
  ps[(size_t)n * 128 + j] = aps;
}

// ============================================================
// K2: degree count
// ============================================================
__global__ __launch_bounds__(256) void count_kernel(
    const int* __restrict__ ei, int* __restrict__ cnt, int E)
{
  const int e = blockIdx.x * 256 + threadIdx.x;
  if (e < E) atomicAdd(&cnt[ei[E + e]], 1);
}

// ============================================================
// K3: exclusive scan of cnt (N = 65536 = 256 threads x 256 elems), one block
// ============================================================
__global__ __launch_bounds__(256) void scan_kernel(
    const int* __restrict__ cnt, int* __restrict__ base, int* __restrict__ fill)
{
  __shared__ int part[256];
  const int tid = threadIdx.x;
  const int c0 = tid * 256;
  int s = 0;
  for (int i = 0; i < 256; ++i) s += cnt[c0 + i];
  part[tid] = s;
  __syncthreads();
  if (tid == 0) {
    int run = 0;
    for (int i = 0; i < 256; ++i) { int t = part[i]; part[i] = run; run += t; }
  }
  __syncthreads();
  int run = part[tid];
  for (int i = 0; i < 256; ++i) {
    int cc = cnt[c0 + i];
    base[c0 + i] = run;
    fill[c0 + i] = run;
    run += cc;
  }
}

// ============================================================
// K4: scatter edge ids + srcs into dst-sorted (CSR) order
// ============================================================
__global__ __launch_bounds__(256) void scatter_kernel(
    const int* __restrict__ ei, int* __restrict__ fill,
    int* __restrict__ eid_s, int* __restrict__ srcs_s, int E)
{
  const int e = blockIdx.x * 256 + threadIdx.x;
  if (e < E) {
    const int d = ei[E + e];
    const int slot = atomicAdd(&fill[d], 1);
    eid_s[slot] = e;
    srcs_s[slot] = ei[e];
  }
}

// ============================================================
// K5: one wave per node. Recompute e from gathered edge_attr rows,
// e-transform, m = etrans + pd + ps[src]; aggregate in registers.
// Writes aggs[n] = {mean(128), max(128), min(128), std(128)}.
// No atomics, no __syncthreads (wave-private LDS only).
// ============================================================
__global__ __launch_bounds__(256) void agg_kernel(
    const float* __restrict__ x, const float* __restrict__ edge_attr,
    const float* __restrict__ W_edge, const float* __restrict__ b_edge,
    const float* __restrict__ W_pre, const float* __restrict__ b_pre,
    const float* __restrict__ ps, const int* __restrict__ eid_s,
    const int* __restrict__ srcs_s, const int* __restrict__ cnt,
    const int* __restrict__ base, float* __restrict__ aggs)
{
  __shared__ float sEA[4][128];   // staged edge_attr row, per wave
  __shared__ float sE[4][32];     // e vector, per wave
  __shared__ float sX[4][128];    // x row, per wave
  const int tid  = threadIdx.x;
  const int lane = tid & 63;
  const int w    = tid >> 6;
  const int g    = lane & 31;
  const int half = lane >> 5;
  const int t0   = half;          // tower of j0 = lane; j1 = lane+64 -> tower t0+2
  const int n    = blockIdx.x * 4 + w;

  // ---- weights in registers ----
  float we[64];                   // W_edge[g][half*64 .. +64)
  {
    const float4* wrow = (const float4*)(W_edge + (size_t)g * 128 + half * 64);
#pragma unroll
    for (int k = 0; k < 16; ++k) {
      const float4 q = wrow[k];
      we[4*k] = q.x; we[4*k+1] = q.y; we[4*k+2] = q.z; we[4*k+3] = q.w;
    }
  }
  float wp0[32], wp1[32];         // W_pre rows 64..95, columns for j0 / j1
#pragma unroll
  for (int f = 0; f < 32; ++f) {
    wp0[f] = W_pre[(size_t)(t0 * 96 + 64 + f) * 32 + g];
    wp1[f] = W_pre[(size_t)((t0 + 2) * 96 + 64 + f) * 32 + g];
  }
  const float bedge = b_edge[g];

  // ---- stage x row, compute pd (dst-part, once per node) ----
  sX[w][lane]      = x[(size_t)n * 128 + lane];
  sX[w][lane + 64] = x[(size_t)n * 128 + 64 + lane];
  float pd0 = b_pre[t0 * 32 + g];
  float pd1 = b_pre[(t0 + 2) * 32 + g];
#pragma unroll
  for (int f = 0; f < 32; ++f) {
    pd0 += sX[w][t0 * 32 + f]       * W_pre[(size_t)(t0 * 96 + f) * 32 + g];
    pd1 += sX[w][(t0 + 2) * 32 + f] * W_pre[(size_t)((t0 + 2) * 96 + f) * 32 + g];
  }

  // ---- edge loop ----
  const int c  = cnt[n];
  const int b0 = base[n];
  float sum0 = 0.f, sum1 = 0.f, sq0 = 0.f, sq1 = 0.f;
  float mx0 = -INFINITY, mx1 = -INFINITY, mn0 = INFINITY, mn1 = INFINITY;
  for (int i = 0; i < c; ++i) {
    const int idx = b0 + i;
    const int eid = eid_s[idx];
    const int s   = srcs_s[idx];
    // stage edge_attr row (2 floats/lane, coalesced 512B)
    const float2 v = *(const float2*)(edge_attr + (size_t)eid * 128 + lane * 2);
    *(float2*)&sEA[w][lane * 2] = v;
    // ps gather (issue early; L3-resident array)
    const float ps0 = ps[(size_t)s * 128 + lane];
    const float ps1 = ps[(size_t)s * 128 + 64 + lane];
    // e[g] = b_edge[g] + ea . W_edge[g,:]  (half-split dot, weights in regs)
    float acc = 0.f;
    const float4* eap = (const float4*)&sEA[w][half * 64];
#pragma unroll
    for (int k = 0; k < 16; ++k) {
      const float4 q = eap[k];
      acc += q.x * we[4*k] + q.y * we[4*k+1] + q.z * we[4*k+2] + q.w * we[4*k+3];
    }
    acc += __shfl_xor(acc, 32);
    sE[w][g] = acc + bedge;       // both halves write identical values
    // etrans: a = e . We_col  (weights in regs, e broadcast from LDS)
    float a0 = 0.f, a1 = 0.f;
    const float4* ep = (const float4*)sE[w];
#pragma unroll
    for (int k = 0; k < 8; ++k) {
      const float4 q = ep[k];
      a0 += q.x * wp0[4*k] + q.y * wp0[4*k+1] + q.z * wp0[4*k+2] + q.w * wp0[4*k+3];
      a1 += q.x * wp1[4*k] + q.y * wp1[4*k+1] + q.z * wp1[4*k+2] + q.w * wp1[4*k+3];
    }
    const float m0 = a0 + pd0 + ps0;
    const float m1 = a1 + pd1 + ps1;
    sum0 += m0; sq0 += m0 * m0; mx0 = fmaxf(mx0, m0); mn0 = fminf(mn0, m0);
    sum1 += m1; sq1 += m1 * m1; mx1 = fmaxf(mx1, m1); mn1 = fminf(mn1, m1);
  }

  // ---- finalize ----
  const float csafe = fmaxf((float)c, 1.f);
  const float mean0 = sum0 / csafe, mean1 = sum1 / csafe;
  const float sd0 = sqrtf(fmaxf(sq0 / csafe - mean0 * mean0, 0.f) + 1e-5f);
  const float sd1 = sqrtf(fmaxf(sq1 / csafe - mean1 * mean1, 0.f) + 1e-5f);
  if (c == 0) { mx0 = mx1 = mn0 = mn1 = 0.f; }
  float* ag = aggs + (size_t)n * 512;
  ag[lane]       = mean0; ag[64 + lane]  = mean1;
  ag[128 + lane] = mx0;   ag[192 + lane] = mx1;
  ag[256 + lane] = mn0;   ag[320 + lane] = mn1;
  ag[384 + lane] = sd0;   ag[448 + lane] = sd1;
}

// ============================================================
// K6: scalers + W_post + W_lin + residual (8 nodes/block, 4-acc W reuse)
// ============================================================
__global__ __launch_bounds__(256) void post_kernel(
    const float* __restrict__ x, const float* __restrict__ aggs,
    const int* __restrict__ cnt,
    const float* __restrict__ W_post, const float* __restrict__ b_post,
    const float* __restrict__ W_lin, const float* __restrict__ b_lin,
    float* __restrict__ out, float avg_log)
{
  __shared__ float vec[8][4][416];
  __shared__ float h2[8][128];
  const int tid = threadIdx.x;
  const int j = tid & 127;
  const int t = j >> 5, g = j & 31;
  const int n0 = blockIdx.x * 8;

  // phase 1: build 416-feature per-tower vectors for 8 nodes
  for (int itn = 0; itn < 4; ++itn) {
    const int nl = itn * 2 + (tid >> 7);
    const int n = n0 + nl;
    const size_t o = (size_t)n * 128 + j;
    const float* ag = aggs + (size_t)n * 512;
    const float c = (float)cnt[n];
    const float mean = ag[j];
    const float mx   = ag[128 + j];
    const float mn   = ag[256 + j];
    const float sd   = ag[384 + j];
    const float logd = logf(c + 1.f);
    const float amp_s = logd / avg_log;
    const float att_s = (c == 0.f) ? 1.f : (avg_log / logd);
    float* v = vec[nl][t];
    v[g]        = x[o];
    v[32 + g]   = mean;          v[64 + g]   = mx;
    v[96 + g]   = mn;            v[128 + g]  = sd;
    v[160 + g]  = mean * amp_s;  v[192 + g]  = mx * amp_s;
    v[224 + g]  = mn * amp_s;    v[256 + g]  = sd * amp_s;
    v[288 + g]  = mean * att_s;  v[320 + g]  = mx * att_s;
    v[352 + g]  = mn * att_s;    v[384 + g]  = sd * att_s;
  }
  __syncthreads();

  // phase 2: h2 = vec @ W_post + b_post (4 node-accs per thread)
  {
    const int nlb = tid >> 7;
    const float b = b_post[t * 32 + g];
    float acc0 = b, acc1 = b, acc2 = b, acc3 = b;
    const float* Wp = W_post + (size_t)(t * 416) * 32 + g;
    const float* v0 = vec[nlb + 0][t];
    const float* v1 = vec[nlb + 2][t];
    const float* v2 = vec[nlb + 4][t];
    const float* v3 = vec[nlb + 6][t];
    for (int f = 0; f < 416; ++f) {
      const float wv = Wp[(size_t)f * 32];
      acc0 += v0[f] * wv; acc1 += v1[f] * wv;
      acc2 += v2[f] * wv; acc3 += v3[f] * wv;
    }
    h2[nlb + 0][j] = acc0; h2[nlb + 2][j] = acc1;
    h2[nlb + 4][j] = acc2; h2[nlb + 6][j] = acc3;
  }
  __syncthreads();

  // phase 3: out = h2 @ W_lin.T + b_lin + x
  {
    const int nlb = tid >> 7;
    const float* Wl = W_lin + (size_t)j * 128;
    const float bl = b_lin[j];
    float a0 = bl, a1 = bl, a2 = bl, a3 = bl;
    const float* h0 = h2[nlb + 0];
    const float* h1 = h2[nlb + 2];
    const float* hp = h2[nlb + 4];
    const float* h3 = h2[nlb + 6];
    for (int k = 0; k < 128; ++k) {
      const float wv = Wl[k];
      a0 += h0[k] * wv; a1 += h1[k] * wv;
      a2 += hp[k] * wv; a3 += h3[k] * wv;
    }
    const size_t b0 = (size_t)(n0 + nlb + 0) * 128 + j;
    const size_t b1 = (size_t)(n0 + nlb + 2) * 128 + j;
    const size_t b2 = (size_t)(n0 + nlb + 4) * 128 + j;
    const size_t b3 = (size_t)(n0 + nlb + 6) * 128 + j;
    out[b0] = a0 + x[b0];
    out[b1] = a1 + x[b1];
    out[b2] = a2 + x[b2];
    out[b3] = a3 + x[b3];
  }
}

extern "C" void kernel_launch(void* const* d_in, const int* in_sizes, int n_in,
                              void* d_out, int out_size, void* d_ws, size_t ws_size,
                              hipStream_t stream) {
  const float* x         = (const float*)d_in[0];
  const float* edge_attr = (const float*)d_in[1];
  const int*   ei        = (const int*)  d_in[2];
  const float* W_edge    = (const float*)d_in[3];
  const float* b_edge    = (const float*)d_in[4];
  const float* W_pre     = (const float*)d_in[5];
  const float* b_pre     = (const float*)d_in[6];
  const float* W_post    = (const float*)d_in[7];
  const float* b_post    = (const float*)d_in[8];
  const float* W_lin     = (const float*)d_in[9];
  const float* b_lin     = (const float*)d_in[10];
  float* out = (float*)d_out;

  const int N = in_sizes[0] / 128;
  const int E = in_sizes[2] / 2;

  // workspace: ps (N*128 f), aggs (N*512 f), eid_s (E), srcs_s (E), cnt/base/fill (N each)
  float* ps    = (float*)d_ws;
  float* aggs  = ps + (size_t)N * 128;
  int*   eid_s = (int*)(aggs + (size_t)N * 512);
  int*   srcs_s = eid_s + E;
  int*   cnt   = srcs_s + E;
  int*   base  = cnt + N;
  int*   fill  = base + N;

  hipMemsetAsync(cnt, 0, (size_t)N * 4, stream);

  const double counts[6] = {108477.0, 299931.0, 180702.0, 10767.0, 3.0, 2.0};
  double num = 0.0, den = 0.0;
  for (int i = 0; i < 6; ++i) { num += counts[i] * log((double)(i + 2)); den += counts[i]; }
  const float avg_log = (float)(num / den);

  pre_kernel<<<N / 2, 256, 0, stream>>>(x, W_pre, ps);
  count_kernel<<<(E + 255) / 256, 256, 0, stream>>>(ei, cnt, E);
  scan_kernel<<<1, 256, 0, stream>>>(cnt, base, fill);
  scatter_kernel<<<(E + 255) / 256, 256, 0, stream>>>(ei, fill, eid_s, srcs_s, E);
  agg_kernel<<<N / 4, 256, 0, stream>>>(x, edge_attr, W_edge, b_edge, W_pre, b_pre,
                                        ps, eid_s, srcs_s, cnt, base, aggs);
  post_kernel<<<N / 8, 256, 0, stream>>>(x, aggs, cnt, W_post, b_post,
                                         W_lin, b_lin, out, avg_log);
}